// Round 4
// baseline (1434.716 us; speedup 1.0000x reference)
//
#include <hip/hip_runtime.h>
#include <cstdint>

constexpr int Bn = 128, Tn = 1024, Dn = 64, Hn = 256, On = 128;

typedef __fp16 h2 __attribute__((ext_vector_type(2)));
typedef unsigned short u16;

__device__ __forceinline__ float fast_tanh(float x) {
  float e = __expf(2.0f * x);
  return 1.0f - 2.0f / (e + 1.0f);
}

// v_dot2_f32_f16: 2 f16 MACs with f32 accumulate, full VALU rate.
__device__ __forceinline__ float fdot2(h2 a, h2 b, float c) {
#if __has_builtin(__builtin_amdgcn_fdot2)
  return __builtin_amdgcn_fdot2(a, b, c, false);
#else
  return fmaf((float)a.y, (float)b.y, fmaf((float)a.x, (float)b.x, c));
#endif
}

__device__ __forceinline__ h2 pk2(float a, float b) {
  h2 r; r.x = (__fp16)a; r.y = (__fp16)b; return r;
}
__device__ __forceinline__ h2 bits2h(unsigned u) { return __builtin_bit_cast(h2, u); }
__device__ __forceinline__ unsigned h2bits(h2 v) { return __builtin_bit_cast(unsigned, v); }
__device__ __forceinline__ u16 f2hb(float f) {
  __fp16 h = (__fp16)f; return __builtin_bit_cast(u16, h);
}
__device__ __forceinline__ float hb2f(u16 b) {
  return (float)__builtin_bit_cast(__fp16, b);
}
// Pin a packed-f16 pair into an ARCH VGPR at this point.
__device__ __forceinline__ void pin16(h2& w) { asm volatile("" : "+v"(w)); }
// Pin a 32-bit value into an AGPR at this point (unified file on gfx950;
// reads from AGPR cost +1 v_accvgpr_read, acceptable off the serial path).
__device__ __forceinline__ void pinA(unsigned& w) { asm volatile("" : "+a"(w)); }

template <int CTRL>
__device__ __forceinline__ float dpp_add(float v) {
  int s = __builtin_amdgcn_update_dpp(0, __float_as_int(v), CTRL, 0xF, 0xF, true);
  return v + __int_as_float(s);
}
__device__ __forceinline__ float row16_sum(float v) {
  v = dpp_add<0xB1>(v);   // quad_perm xor1
  v = dpp_add<0x4E>(v);   // quad_perm xor2
  v = dpp_add<0x141>(v);  // ROW_HALF_MIRROR == xor4
  v = dpp_add<0x140>(v);  // ROW_MIRROR == xor8
  return v;
}
__device__ __forceinline__ float sel8(int ks, float s0, float s1, float s2,
                                      float s3, float s4, float s5, float s6,
                                      float s7) {
  float u0 = (ks & 1) ? s1 : s0;
  float u1 = (ks & 1) ? s3 : s2;
  float u2 = (ks & 1) ? s5 : s4;
  float u3 = (ks & 1) ? s7 : s6;
  float v0 = (ks & 2) ? u1 : u0;
  float v1 = (ks & 2) ? u3 : u2;
  return (ks & 4) ? v1 : v0;
}

// Full 256-k matvec for one LDS row (stride-320-half layout, 20*ks chunks):
// every lane computes 8 column partials, DPP-reduces over the 16 ks lanes,
// and returns this lane's selected column value (pre-bias).
__device__ __forceinline__ float colval256(const u16* rowbase, int ks,
                                           const h2 (&w)[8][8]) {
  const uint2* hq = (const uint2*)(rowbase + 20 * ks);
  uint2 q0 = hq[0], q1 = hq[1], q2 = hq[2], q3 = hq[3];
  float a0 = 0.f, a1 = 0.f, a2 = 0.f, a3 = 0.f,
        a4 = 0.f, a5 = 0.f, a6 = 0.f, a7 = 0.f;
  const unsigned d[8] = {q0.x, q0.y, q1.x, q1.y, q2.x, q2.y, q3.x, q3.y};
  #pragma unroll
  for (int p = 0; p < 8; ++p) {
    h2 hp = bits2h(d[p]);
    a0 = fdot2(hp, w[p][0], a0);
    a1 = fdot2(hp, w[p][1], a1);
    a2 = fdot2(hp, w[p][2], a2);
    a3 = fdot2(hp, w[p][3], a3);
    a4 = fdot2(hp, w[p][4], a4);
    a5 = fdot2(hp, w[p][5], a5);
    a6 = fdot2(hp, w[p][6], a6);
    a7 = fdot2(hp, w[p][7], a7);
  }
  float s0 = row16_sum(a0), s1 = row16_sum(a1);
  float s2 = row16_sum(a2), s3 = row16_sum(a3);
  float s4 = row16_sum(a4), s5 = row16_sum(a5);
  float s6 = row16_sum(a6), s7 = row16_sum(a7);
  return sel8(ks, s0, s1, s2, s3, s4, s5, s6, s7);
}

// Same matvec but with AGPR-resident weights (unsigned storage, bit-cast at
// use -> compiler emits v_accvgpr_read per weight; throughput path only).
__device__ __forceinline__ float colval256u(const u16* rowbase, int ks,
                                            const unsigned (&wb)[8][8]) {
  const uint2* hq = (const uint2*)(rowbase + 20 * ks);
  uint2 q0 = hq[0], q1 = hq[1], q2 = hq[2], q3 = hq[3];
  float a0 = 0.f, a1 = 0.f, a2 = 0.f, a3 = 0.f,
        a4 = 0.f, a5 = 0.f, a6 = 0.f, a7 = 0.f;
  const unsigned d[8] = {q0.x, q0.y, q1.x, q1.y, q2.x, q2.y, q3.x, q3.y};
  #pragma unroll
  for (int p = 0; p < 8; ++p) {
    h2 hp = bits2h(d[p]);
    a0 = fdot2(hp, bits2h(wb[p][0]), a0);
    a1 = fdot2(hp, bits2h(wb[p][1]), a1);
    a2 = fdot2(hp, bits2h(wb[p][2]), a2);
    a3 = fdot2(hp, bits2h(wb[p][3]), a3);
    a4 = fdot2(hp, bits2h(wb[p][4]), a4);
    a5 = fdot2(hp, bits2h(wb[p][5]), a5);
    a6 = fdot2(hp, bits2h(wb[p][6]), a6);
    a7 = fdot2(hp, bits2h(wb[p][7]), a7);
  }
  float s0 = row16_sum(a0), s1 = row16_sum(a1);
  float s2 = row16_sum(a2), s3 = row16_sum(a3);
  float s4 = row16_sum(a4), s5 = row16_sum(a5);
  float s6 = row16_sum(a6), s7 = row16_sum(a7);
  return sel8(ks, s0, s1, s2, s3, s4, s5, s6, s7);
}

// LDS h layout (f16): 16 slices x (16 data + 4 pad) halfs; slice stride 40 B
// -> reader dwords 10*ks mod 32 all distinct, conflict-free; 8 B aligned.
// ---------------------------------------------------------------------------
// Fused pipeline, 256 WGs == 256 CUs -> guaranteed one block per CU.
//   role A  (blocks   0..127): scan1 producer -> h1 to global + flags
//   role BC (blocks 128..255): per 32-step chunk: stage h1, u2 rows 0..7
//       dense, then 32 serial scan2 steps with u2 row s+8 interleaved into
//       step s. Register discipline (round-2/3 lessons):
//       - __launch_bounds__(512,2): budget 256 unified regs/wave. (512,1)
//         allowed >256 VGPRs -> 512-thread block unlaunchable -> HANG.
//       - w2 (dense-phase weights) pinned "+a" -> AGPRs; accvgpr_read cost
//         lands on the slack-rich throughput path.
//       - wh2 (serial-phase weights) pinned "+v" per chunk -> arch VGPRs;
//         the 64 weight reads per serial step are direct operands again
//         (round 2: both sets contended for 128 arch regs -> serial step
//         0.61 -> 1.25 us from accvgpr reads on the critical path).
// ---------------------------------------------------------------------------
__global__ __launch_bounds__(512, 2) void stage1_kernel(
    const float* __restrict__ x,    // [B,T,64] f32
    const float* __restrict__ Wx1,  // [64,256] f32
    const float* __restrict__ Wh1,  // [256,256] f32
    const float* __restrict__ b1,   // [256]
    const float* __restrict__ Wx2,  // [256,256] f32
    const float* __restrict__ b2,   // [256]
    const float* __restrict__ Wh2,  // [256,256] f32
    u16* __restrict__ h1b16,        // [B,T,256] f16 h1 (A -> BC channel)
    int* __restrict__ flags,        // [B]  A -> BC progress (32-step blocks)
    float* __restrict__ hfinal) {   // [B,256] f32 (role BC output)
  __shared__ alignas(16) u16 smemU[19584];  // 38.25 KB
  const int tid = threadIdx.x;
  const int ks = tid & 15;
  const int cg = tid >> 4;
  const int col0 = 8 * cg;
  const int jcol = col0 + (ks & 7);
  const bool writer = (ks < 8);
  const unsigned bid = blockIdx.x;

  if (bid < (unsigned)Bn) {
    // ================= ROLE A: scan1 producer =================
    const int b = bid;
    const float* xb = x + (size_t)b * Tn * Dn;
    u16* hb = h1b16 + (size_t)b * Tn * Hn;
    u16* hcH = smemU;          // 2 x 320 halfs
    u16* xsH = smemU + 768;    // 2 x 2048 halfs (32-step x blocks, f16)

    h2 wh[8][8];  // Wh1 k-pairs (16ks+2p, +1) x 8 cols
    #pragma unroll
    for (int p = 0; p < 8; ++p) {
      const float* r0 = Wh1 + (size_t)(16 * ks + 2 * p) * Hn + col0;
      float4 a0 = *(const float4*)r0, a1 = *(const float4*)(r0 + 4);
      float4 c0 = *(const float4*)(r0 + Hn), c1 = *(const float4*)(r0 + Hn + 4);
      wh[p][0] = pk2(a0.x, c0.x); wh[p][1] = pk2(a0.y, c0.y);
      wh[p][2] = pk2(a0.z, c0.z); wh[p][3] = pk2(a0.w, c0.w);
      wh[p][4] = pk2(a1.x, c1.x); wh[p][5] = pk2(a1.y, c1.y);
      wh[p][6] = pk2(a1.z, c1.z); wh[p][7] = pk2(a1.w, c1.w);
    }
    h2 wx[2][8];  // Wx1 k-pairs (4ks+2p, +1)
    #pragma unroll
    for (int p = 0; p < 2; ++p) {
      const float* r0 = Wx1 + (size_t)(4 * ks + 2 * p) * Hn + col0;
      float4 a0 = *(const float4*)r0, a1 = *(const float4*)(r0 + 4);
      float4 c0 = *(const float4*)(r0 + Hn), c1 = *(const float4*)(r0 + Hn + 4);
      wx[p][0] = pk2(a0.x, c0.x); wx[p][1] = pk2(a0.y, c0.y);
      wx[p][2] = pk2(a0.z, c0.z); wx[p][3] = pk2(a0.w, c0.w);
      wx[p][4] = pk2(a1.x, c1.x); wx[p][5] = pk2(a1.y, c1.y);
      wx[p][6] = pk2(a1.z, c1.z); wx[p][7] = pk2(a1.w, c1.w);
    }
    #pragma unroll
    for (int p = 0; p < 8; ++p)
      #pragma unroll
      for (int c = 0; c < 8; ++c) pin16(wh[p][c]);
    #pragma unroll
    for (int p = 0; p < 2; ++p)
      #pragma unroll
      for (int c = 0; c < 8; ++c) pin16(wx[p][c]);

    const float bj = b1[jcol];
    const int woffH = 20 * (jcol >> 4) + (jcol & 15);

    for (int i = tid; i < 640; i += 512) hcH[i] = 0;  // zero both h buffers
    {
      float4 x0 = *(const float4*)(xb + 4 * tid);  // block 0 -> f16 LDS
      ((uint2*)xsH)[tid] = make_uint2(h2bits(pk2(x0.x, x0.y)), h2bits(pk2(x0.z, x0.w)));
    }
    __syncthreads();

    u16 hreg[8];
    float4 xr = make_float4(0.f, 0.f, 0.f, 0.f);
    for (int t8 = 0; t8 < 128; ++t8) {
      const int xcur = (t8 >> 2) & 1;
      #pragma unroll
      for (int s = 0; s < 8; ++s) {
        const int t = t8 * 8 + s;
        const int cu = s & 1, nx = cu ^ 1;
        if (s == 0 && (t8 & 3) == 0 && t8 < 124)
          xr = *(const float4*)(xb + (size_t)((t8 >> 2) + 1) * 2048 + 4 * tid);

        const uint2* hq = (const uint2*)(hcH + cu * 320 + 20 * ks);
        uint2 q0 = hq[0], q1 = hq[1], q2 = hq[2], q3 = hq[3];
        uint2 xq = *(const uint2*)(xsH + xcur * 2048 + ((t & 31) << 6) + 4 * ks);
        float a0 = 0.f, a1 = 0.f, a2 = 0.f, a3 = 0.f,
              a4 = 0.f, a5 = 0.f, a6 = 0.f, a7 = 0.f;
        const unsigned d[8] = {q0.x, q0.y, q1.x, q1.y, q2.x, q2.y, q3.x, q3.y};
        #pragma unroll
        for (int p = 0; p < 8; ++p) {
          h2 hp = bits2h(d[p]);
          a0 = fdot2(hp, wh[p][0], a0);
          a1 = fdot2(hp, wh[p][1], a1);
          a2 = fdot2(hp, wh[p][2], a2);
          a3 = fdot2(hp, wh[p][3], a3);
          a4 = fdot2(hp, wh[p][4], a4);
          a5 = fdot2(hp, wh[p][5], a5);
          a6 = fdot2(hp, wh[p][6], a6);
          a7 = fdot2(hp, wh[p][7], a7);
        }
        {
          h2 xp0 = bits2h(xq.x), xp1 = bits2h(xq.y);
          a0 = fdot2(xp0, wx[0][0], a0); a0 = fdot2(xp1, wx[1][0], a0);
          a1 = fdot2(xp0, wx[0][1], a1); a1 = fdot2(xp1, wx[1][1], a1);
          a2 = fdot2(xp0, wx[0][2], a2); a2 = fdot2(xp1, wx[1][2], a2);
          a3 = fdot2(xp0, wx[0][3], a3); a3 = fdot2(xp1, wx[1][3], a3);
          a4 = fdot2(xp0, wx[0][4], a4); a4 = fdot2(xp1, wx[1][4], a4);
          a5 = fdot2(xp0, wx[0][5], a5); a5 = fdot2(xp1, wx[1][5], a5);
          a6 = fdot2(xp0, wx[0][6], a6); a6 = fdot2(xp1, wx[1][6], a6);
          a7 = fdot2(xp0, wx[0][7], a7); a7 = fdot2(xp1, wx[1][7], a7);
        }
        float s0 = row16_sum(a0), s1 = row16_sum(a1);
        float s2 = row16_sum(a2), s3 = row16_sum(a3);
        float s4 = row16_sum(a4), s5 = row16_sum(a5);
        float s6 = row16_sum(a6), s7 = row16_sum(a7);
        float h = fast_tanh(sel8(ks, s0, s1, s2, s3, s4, s5, s6, s7) + bj);
        u16 hbits = f2hb(h);
        if (writer) hcH[nx * 320 + woffH] = hbits;
        hreg[s] = hbits;
        if (s == 7) {
          if (writer) {
            u16* dst = hb + (size_t)(t - 7) * Hn + jcol;
            #pragma unroll
            for (int i = 0; i < 8; ++i) dst[i * Hn] = hreg[i];
          }
          if ((t8 & 3) == 3 && t8 < 127)
            ((uint2*)(xsH + (xcur ^ 1) * 2048))[tid] =
                make_uint2(h2bits(pk2(xr.x, xr.y)), h2bits(pk2(xr.z, xr.w)));
        }
        __syncthreads();  // vmcnt(0) drained -> safe to release
        if (s == 7 && (t8 & 3) == 3 && tid == 0)
          __hip_atomic_store(flags + b, (t8 >> 2) + 1, __ATOMIC_RELEASE,
                             __HIP_MEMORY_SCOPE_AGENT);
      }
    }
  } else {
    // ========== ROLE BC: u2 = h1@Wx2+b2 (LDS) fused with scan2 ===========
    const int b = bid - Bn;
    const u16* hb1 = h1b16 + (size_t)b * Tn * Hn;
    u16* hsH = smemU;            // [32][320] halfs = 20 KB (h1 staging)
    u16* u2S = smemU + 10240;    // [32][272] halfs = 17 KB (u2 buffer)
    u16* hcU = smemU + 18944;    // 2 x 320 halfs (h2 state)

    unsigned w2b[8][8];  // Wx2 k-pairs -> AGPR-resident (throughput path)
    h2 wh[8][8];         // Wh2 k-pairs -> arch-VGPR (serial-critical path)
    #pragma unroll
    for (int p = 0; p < 8; ++p) {
      const float* r0 = Wx2 + (size_t)(16 * ks + 2 * p) * Hn + col0;
      float4 a0 = *(const float4*)r0, a1 = *(const float4*)(r0 + 4);
      float4 c0 = *(const float4*)(r0 + Hn), c1 = *(const float4*)(r0 + Hn + 4);
      w2b[p][0] = h2bits(pk2(a0.x, c0.x)); w2b[p][1] = h2bits(pk2(a0.y, c0.y));
      w2b[p][2] = h2bits(pk2(a0.z, c0.z)); w2b[p][3] = h2bits(pk2(a0.w, c0.w));
      w2b[p][4] = h2bits(pk2(a1.x, c1.x)); w2b[p][5] = h2bits(pk2(a1.y, c1.y));
      w2b[p][6] = h2bits(pk2(a1.z, c1.z)); w2b[p][7] = h2bits(pk2(a1.w, c1.w));
    }
    #pragma unroll
    for (int p = 0; p < 8; ++p) {
      const float* r0 = Wh2 + (size_t)(16 * ks + 2 * p) * Hn + col0;
      float4 a0 = *(const float4*)r0, a1 = *(const float4*)(r0 + 4);
      float4 c0 = *(const float4*)(r0 + Hn), c1 = *(const float4*)(r0 + Hn + 4);
      wh[p][0] = pk2(a0.x, c0.x); wh[p][1] = pk2(a0.y, c0.y);
      wh[p][2] = pk2(a0.z, c0.z); wh[p][3] = pk2(a0.w, c0.w);
      wh[p][4] = pk2(a1.x, c1.x); wh[p][5] = pk2(a1.y, c1.y);
      wh[p][6] = pk2(a1.z, c1.z); wh[p][7] = pk2(a1.w, c1.w);
    }
    #pragma unroll
    for (int p = 0; p < 8; ++p)
      #pragma unroll
      for (int c = 0; c < 8; ++c) { pinA(w2b[p][c]); pin16(wh[p][c]); }

    const float b2j = b2[jcol];
    const int woffH = 20 * (jcol >> 4) + (jcol & 15);
    const int lr = tid >> 4;            // step row within chunk
    const int lc = tid & 15;            // 16-half column chunk
    u16* ldst = hsH + lr * 320 + 20 * lc;

    for (int i = tid; i < 640; i += 512) hcU[i] = 0;  // zero h2 state

    for (int blk = 0; blk < 32; ++blk) {
      if (tid == 0) {
        while (__hip_atomic_load(flags + b, __ATOMIC_ACQUIRE,
                                 __HIP_MEMORY_SCOPE_AGENT) < blk + 1)
          __builtin_amdgcn_s_sleep(8);
      }
      __syncthreads();
      {  // stage h1 chunk [32 steps][256] -> hsH
        const uint4* src = (const uint4*)(hb1 + (size_t)(blk * 32 + lr) * Hn + 16 * lc);
        uint4 v0 = src[0], v1 = src[1];  // 32 B = 16 halfs
        ((uint2*)ldst)[0] = make_uint2(v0.x, v0.y);
        ((uint2*)ldst)[1] = make_uint2(v0.z, v0.w);
        ((uint2*)ldst)[2] = make_uint2(v1.x, v1.y);
        ((uint2*)ldst)[3] = make_uint2(v1.z, v1.w);
      }
      __syncthreads();
      // u2 for steps 0..7 of this chunk (steps 8..31 fill in during scan)
      #pragma unroll
      for (int q = 0; q < 8; ++q) {
        float v = colval256u(hsH + q * 320, ks, w2b);
        if (writer) u2S[q * 272 + jcol] = f2hb(v + b2j);
      }
      // Re-assert wh in arch VGPRs for the serial loop (at most 64
      // accvgpr_reads per CHUNK here, instead of 64 per STEP inside).
      #pragma unroll
      for (int p = 0; p < 8; ++p)
        #pragma unroll
        for (int c = 0; c < 8; ++c) pin16(wh[p][c]);
      __syncthreads();
      // 32 serial scan steps; interleave u2 compute for step+8 (indep work)
      for (int g = 0; g < 4; ++g) {
        #pragma unroll
        for (int s = 0; s < 8; ++s) {
          const int step = g * 8 + s;
          const int cu = step & 1, nx = cu ^ 1;
          float uval = 0.f;
          if (writer) uval = hb2f(u2S[step * 272 + jcol]);
          float acc = colval256(hcU + cu * 320, ks, wh);
          if (g < 3) {  // fill u2 for step+8 into the latency bubbles
            float v = colval256u(hsH + (step + 8) * 320, ks, w2b);
            if (writer) u2S[(step + 8) * 272 + jcol] = f2hb(v + b2j);
          }
          float h = fast_tanh(acc + uval);
          if (writer) hcU[nx * 320 + woffH] = f2hb(h);
          __syncthreads();
        }
      }
    }
    if (tid < Hn)
      hfinal[(size_t)b * Hn + tid] = hb2f(hcU[(tid >> 4) * 20 + (tid & 15)]);
  }
}

// ---------------------------------------------------------------------------
// Head: out = softmax(h2_T @ Wd + bd). f32, unchanged.
// ---------------------------------------------------------------------------
__global__ __launch_bounds__(128) void head_kernel(
    const float* __restrict__ hfinal, const float* __restrict__ Wd,
    const float* __restrict__ bd, float* __restrict__ out) {
  __shared__ float hrow[Hn];
  __shared__ float red[On];
  const int o = threadIdx.x;
  const int b = blockIdx.x;
  hrow[o] = hfinal[(size_t)b * Hn + o];
  hrow[o + 128] = hfinal[(size_t)b * Hn + 128 + o];
  __syncthreads();
  float acc = bd[o];
  #pragma unroll 8
  for (int k = 0; k < Hn; ++k) acc = fmaf(hrow[k], Wd[(size_t)k * On + o], acc);
  red[o] = acc;
  __syncthreads();
  #pragma unroll
  for (int s = 64; s > 0; s >>= 1) {
    if (o < s) red[o] = fmaxf(red[o], red[o + s]);
    __syncthreads();
  }
  const float mx = red[0];
  __syncthreads();
  const float e = __expf(acc - mx);
  red[o] = e;
  __syncthreads();
  #pragma unroll
  for (int s = 64; s > 0; s >>= 1) {
    if (o < s) red[o] += red[o + s];
    __syncthreads();
  }
  out[(size_t)b * On + o] = e / red[0];
}

// ---------------------------------------------------------------------------
extern "C" void kernel_launch(void* const* d_in, const int* in_sizes, int n_in,
                              void* d_out, int out_size, void* d_ws, size_t ws_size,
                              hipStream_t stream) {
  const float* x   = (const float*)d_in[0];
  const float* Wx1 = (const float*)d_in[1];
  const float* Wh1 = (const float*)d_in[2];
  const float* b1  = (const float*)d_in[3];
  const float* Wx2 = (const float*)d_in[4];
  const float* Wh2 = (const float*)d_in[5];
  const float* b2  = (const float*)d_in[6];
  const float* Wd  = (const float*)d_in[7];
  const float* bd  = (const float*)d_in[8];
  float* out = (float*)d_out;

  u16* h1b16 = (u16*)d_ws;                            // [B,T,256] f16 (64 MB)
  float* hfinal = (float*)(h1b16 + (size_t)Bn * Tn * Hn);  // [B,256] f32
  int* flags = (int*)(hfinal + (size_t)Bn * Hn);      // [B] A->BC

  hipMemsetAsync(flags, 0, Bn * sizeof(int), stream);
  stage1_kernel<<<2 * Bn, 512, 0, stream>>>(x, Wx1, Wh1, b1, Wx2, b2, Wh2,
                                            h1b16, flags, hfinal);
  head_kernel<<<Bn, 128, 0, stream>>>(hfinal, Wd, bd, out);
}

// Round 5
// 1301.070 us; speedup vs baseline: 1.1027x; 1.1027x over previous
//
#include <hip/hip_runtime.h>
#include <cstdint>

constexpr int Bn = 128, Tn = 1024, Dn = 64, Hn = 256, On = 128;

typedef __fp16 h2 __attribute__((ext_vector_type(2)));
typedef unsigned short u16;

__device__ __forceinline__ float fast_tanh(float x) {
  float e = __expf(2.0f * x);
  return 1.0f - 2.0f / (e + 1.0f);
}

// v_dot2_f32_f16: 2 f16 MACs with f32 accumulate, full VALU rate.
__device__ __forceinline__ float fdot2(h2 a, h2 b, float c) {
#if __has_builtin(__builtin_amdgcn_fdot2)
  return __builtin_amdgcn_fdot2(a, b, c, false);
#else
  return fmaf((float)a.y, (float)b.y, fmaf((float)a.x, (float)b.x, c));
#endif
}

__device__ __forceinline__ h2 pk2(float a, float b) {
  h2 r; r.x = (__fp16)a; r.y = (__fp16)b; return r;
}
__device__ __forceinline__ h2 bits2h(unsigned u) { return __builtin_bit_cast(h2, u); }
__device__ __forceinline__ unsigned h2bits(h2 v) { return __builtin_bit_cast(unsigned, v); }
__device__ __forceinline__ u16 f2hb(float f) {
  __fp16 h = (__fp16)f; return __builtin_bit_cast(u16, h);
}
__device__ __forceinline__ float hb2f(u16 b) {
  return (float)__builtin_bit_cast(__fp16, b);
}
// Pin a packed-f16 pair into an ARCH VGPR at this point.
__device__ __forceinline__ void pin16(h2& w) { asm volatile("" : "+v"(w)); }
// Pin a 32-bit value into an AGPR at this point (unified file on gfx950;
// reads from AGPR cost +1 v_accvgpr_read, acceptable off the serial path).
__device__ __forceinline__ void pinA(unsigned& w) { asm volatile("" : "+a"(w)); }

template <int CTRL>
__device__ __forceinline__ float dpp_add(float v) {
  int s = __builtin_amdgcn_update_dpp(0, __float_as_int(v), CTRL, 0xF, 0xF, true);
  return v + __int_as_float(s);
}
__device__ __forceinline__ float row16_sum(float v) {
  v = dpp_add<0xB1>(v);   // quad_perm xor1
  v = dpp_add<0x4E>(v);   // quad_perm xor2
  v = dpp_add<0x141>(v);  // ROW_HALF_MIRROR == xor4
  v = dpp_add<0x140>(v);  // ROW_MIRROR == xor8
  return v;
}
__device__ __forceinline__ float sel8(int ks, float s0, float s1, float s2,
                                      float s3, float s4, float s5, float s6,
                                      float s7) {
  float u0 = (ks & 1) ? s1 : s0;
  float u1 = (ks & 1) ? s3 : s2;
  float u2 = (ks & 1) ? s5 : s4;
  float u3 = (ks & 1) ? s7 : s6;
  float v0 = (ks & 2) ? u1 : u0;
  float v1 = (ks & 2) ? u3 : u2;
  return (ks & 4) ? v1 : v0;
}

// Full 256-k matvec for one LDS row (stride-320-half layout, 20*ks chunks):
// every lane computes 8 column partials, DPP-reduces over the 16 ks lanes,
// and returns this lane's selected column value (pre-bias).
__device__ __forceinline__ float colval256(const u16* rowbase, int ks,
                                           const h2 (&w)[8][8]) {
  const uint2* hq = (const uint2*)(rowbase + 20 * ks);
  uint2 q0 = hq[0], q1 = hq[1], q2 = hq[2], q3 = hq[3];
  float a0 = 0.f, a1 = 0.f, a2 = 0.f, a3 = 0.f,
        a4 = 0.f, a5 = 0.f, a6 = 0.f, a7 = 0.f;
  const unsigned d[8] = {q0.x, q0.y, q1.x, q1.y, q2.x, q2.y, q3.x, q3.y};
  #pragma unroll
  for (int p = 0; p < 8; ++p) {
    h2 hp = bits2h(d[p]);
    a0 = fdot2(hp, w[p][0], a0);
    a1 = fdot2(hp, w[p][1], a1);
    a2 = fdot2(hp, w[p][2], a2);
    a3 = fdot2(hp, w[p][3], a3);
    a4 = fdot2(hp, w[p][4], a4);
    a5 = fdot2(hp, w[p][5], a5);
    a6 = fdot2(hp, w[p][6], a6);
    a7 = fdot2(hp, w[p][7], a7);
  }
  float s0 = row16_sum(a0), s1 = row16_sum(a1);
  float s2 = row16_sum(a2), s3 = row16_sum(a3);
  float s4 = row16_sum(a4), s5 = row16_sum(a5);
  float s6 = row16_sum(a6), s7 = row16_sum(a7);
  return sel8(ks, s0, s1, s2, s3, s4, s5, s6, s7);
}

// Same matvec but with AGPR-resident weights (unsigned storage, bit-cast at
// use -> compiler emits v_accvgpr_read per weight; throughput path only).
__device__ __forceinline__ float colval256u(const u16* rowbase, int ks,
                                            const unsigned (&wb)[8][8]) {
  const uint2* hq = (const uint2*)(rowbase + 20 * ks);
  uint2 q0 = hq[0], q1 = hq[1], q2 = hq[2], q3 = hq[3];
  float a0 = 0.f, a1 = 0.f, a2 = 0.f, a3 = 0.f,
        a4 = 0.f, a5 = 0.f, a6 = 0.f, a7 = 0.f;
  const unsigned d[8] = {q0.x, q0.y, q1.x, q1.y, q2.x, q2.y, q3.x, q3.y};
  #pragma unroll
  for (int p = 0; p < 8; ++p) {
    h2 hp = bits2h(d[p]);
    a0 = fdot2(hp, bits2h(wb[p][0]), a0);
    a1 = fdot2(hp, bits2h(wb[p][1]), a1);
    a2 = fdot2(hp, bits2h(wb[p][2]), a2);
    a3 = fdot2(hp, bits2h(wb[p][3]), a3);
    a4 = fdot2(hp, bits2h(wb[p][4]), a4);
    a5 = fdot2(hp, bits2h(wb[p][5]), a5);
    a6 = fdot2(hp, bits2h(wb[p][6]), a6);
    a7 = fdot2(hp, bits2h(wb[p][7]), a7);
  }
  float s0 = row16_sum(a0), s1 = row16_sum(a1);
  float s2 = row16_sum(a2), s3 = row16_sum(a3);
  float s4 = row16_sum(a4), s5 = row16_sum(a5);
  float s6 = row16_sum(a6), s7 = row16_sum(a7);
  return sel8(ks, s0, s1, s2, s3, s4, s5, s6, s7);
}

// LDS h layout (f16): 16 slices x (16 data + 4 pad) halfs; slice stride 40 B
// -> reader dwords 10*ks mod 32 all distinct, conflict-free; 8 B aligned.
// ---------------------------------------------------------------------------
// Fused pipeline, 256 WGs == 256 CUs -> guaranteed one block per CU.
//   role A  (blocks   0..127): scan1 producer -> h1 to global + flags
//   role BC (blocks 128..255): per 32-step chunk:
//       stage h1 -> DENSE PROLOGUE: all 32 u2 rows (u2 = h1@Wx2+b2 -> LDS,
//       never global) -> 32 CLEAN serial scan2 steps.
//   Hard-won rules encoded here:
//   - (512,2) launch bounds: (512,1) allows >256 VGPR/wave -> 512-thread
//     block unlaunchable -> device hang (round 3).
//   - w2 pinned "+a" (AGPR), wh pinned "+v" (arch VGPR), ONCE at init.
//     Round 4 proved this split works (VGPR_Count=104 = wh 64 + working 40).
//   - NO work interleaved into the serial scan loop: rounds 2 & 4 both
//     showed an interleaved u2 row costs ~4x its issue estimate inside the
//     barrier-locked latency-bound loop (0.61 -> 1.25/1.46 us per step).
//     Dense burst runs as a prologue instead (role-B-measured ~8 us clean,
//     ~11 us with accvgpr reads; slack-rich throughput phase).
// ---------------------------------------------------------------------------
__global__ __launch_bounds__(512, 2) void stage1_kernel(
    const float* __restrict__ x,    // [B,T,64] f32
    const float* __restrict__ Wx1,  // [64,256] f32
    const float* __restrict__ Wh1,  // [256,256] f32
    const float* __restrict__ b1,   // [256]
    const float* __restrict__ Wx2,  // [256,256] f32
    const float* __restrict__ b2,   // [256]
    const float* __restrict__ Wh2,  // [256,256] f32
    u16* __restrict__ h1b16,        // [B,T,256] f16 h1 (A -> BC channel)
    int* __restrict__ flags,        // [B]  A -> BC progress (32-step blocks)
    float* __restrict__ hfinal) {   // [B,256] f32 (role BC output)
  __shared__ alignas(16) u16 smemU[19584];  // 38.25 KB
  const int tid = threadIdx.x;
  const int ks = tid & 15;
  const int cg = tid >> 4;
  const int col0 = 8 * cg;
  const int jcol = col0 + (ks & 7);
  const bool writer = (ks < 8);
  const unsigned bid = blockIdx.x;

  if (bid < (unsigned)Bn) {
    // ================= ROLE A: scan1 producer =================
    const int b = bid;
    const float* xb = x + (size_t)b * Tn * Dn;
    u16* hb = h1b16 + (size_t)b * Tn * Hn;
    u16* hcH = smemU;          // 2 x 320 halfs
    u16* xsH = smemU + 768;    // 2 x 2048 halfs (32-step x blocks, f16)

    h2 wh[8][8];  // Wh1 k-pairs (16ks+2p, +1) x 8 cols
    #pragma unroll
    for (int p = 0; p < 8; ++p) {
      const float* r0 = Wh1 + (size_t)(16 * ks + 2 * p) * Hn + col0;
      float4 a0 = *(const float4*)r0, a1 = *(const float4*)(r0 + 4);
      float4 c0 = *(const float4*)(r0 + Hn), c1 = *(const float4*)(r0 + Hn + 4);
      wh[p][0] = pk2(a0.x, c0.x); wh[p][1] = pk2(a0.y, c0.y);
      wh[p][2] = pk2(a0.z, c0.z); wh[p][3] = pk2(a0.w, c0.w);
      wh[p][4] = pk2(a1.x, c1.x); wh[p][5] = pk2(a1.y, c1.y);
      wh[p][6] = pk2(a1.z, c1.z); wh[p][7] = pk2(a1.w, c1.w);
    }
    h2 wx[2][8];  // Wx1 k-pairs (4ks+2p, +1)
    #pragma unroll
    for (int p = 0; p < 2; ++p) {
      const float* r0 = Wx1 + (size_t)(4 * ks + 2 * p) * Hn + col0;
      float4 a0 = *(const float4*)r0, a1 = *(const float4*)(r0 + 4);
      float4 c0 = *(const float4*)(r0 + Hn), c1 = *(const float4*)(r0 + Hn + 4);
      wx[p][0] = pk2(a0.x, c0.x); wx[p][1] = pk2(a0.y, c0.y);
      wx[p][2] = pk2(a0.z, c0.z); wx[p][3] = pk2(a0.w, c0.w);
      wx[p][4] = pk2(a1.x, c1.x); wx[p][5] = pk2(a1.y, c1.y);
      wx[p][6] = pk2(a1.z, c1.z); wx[p][7] = pk2(a1.w, c1.w);
    }
    #pragma unroll
    for (int p = 0; p < 8; ++p)
      #pragma unroll
      for (int c = 0; c < 8; ++c) pin16(wh[p][c]);
    #pragma unroll
    for (int p = 0; p < 2; ++p)
      #pragma unroll
      for (int c = 0; c < 8; ++c) pin16(wx[p][c]);

    const float bj = b1[jcol];
    const int woffH = 20 * (jcol >> 4) + (jcol & 15);

    for (int i = tid; i < 640; i += 512) hcH[i] = 0;  // zero both h buffers
    {
      float4 x0 = *(const float4*)(xb + 4 * tid);  // block 0 -> f16 LDS
      ((uint2*)xsH)[tid] = make_uint2(h2bits(pk2(x0.x, x0.y)), h2bits(pk2(x0.z, x0.w)));
    }
    __syncthreads();

    u16 hreg[8];
    float4 xr = make_float4(0.f, 0.f, 0.f, 0.f);
    for (int t8 = 0; t8 < 128; ++t8) {
      const int xcur = (t8 >> 2) & 1;
      #pragma unroll
      for (int s = 0; s < 8; ++s) {
        const int t = t8 * 8 + s;
        const int cu = s & 1, nx = cu ^ 1;
        if (s == 0 && (t8 & 3) == 0 && t8 < 124)
          xr = *(const float4*)(xb + (size_t)((t8 >> 2) + 1) * 2048 + 4 * tid);

        const uint2* hq = (const uint2*)(hcH + cu * 320 + 20 * ks);
        uint2 q0 = hq[0], q1 = hq[1], q2 = hq[2], q3 = hq[3];
        uint2 xq = *(const uint2*)(xsH + xcur * 2048 + ((t & 31) << 6) + 4 * ks);
        float a0 = 0.f, a1 = 0.f, a2 = 0.f, a3 = 0.f,
              a4 = 0.f, a5 = 0.f, a6 = 0.f, a7 = 0.f;
        const unsigned d[8] = {q0.x, q0.y, q1.x, q1.y, q2.x, q2.y, q3.x, q3.y};
        #pragma unroll
        for (int p = 0; p < 8; ++p) {
          h2 hp = bits2h(d[p]);
          a0 = fdot2(hp, wh[p][0], a0);
          a1 = fdot2(hp, wh[p][1], a1);
          a2 = fdot2(hp, wh[p][2], a2);
          a3 = fdot2(hp, wh[p][3], a3);
          a4 = fdot2(hp, wh[p][4], a4);
          a5 = fdot2(hp, wh[p][5], a5);
          a6 = fdot2(hp, wh[p][6], a6);
          a7 = fdot2(hp, wh[p][7], a7);
        }
        {
          h2 xp0 = bits2h(xq.x), xp1 = bits2h(xq.y);
          a0 = fdot2(xp0, wx[0][0], a0); a0 = fdot2(xp1, wx[1][0], a0);
          a1 = fdot2(xp0, wx[0][1], a1); a1 = fdot2(xp1, wx[1][1], a1);
          a2 = fdot2(xp0, wx[0][2], a2); a2 = fdot2(xp1, wx[1][2], a2);
          a3 = fdot2(xp0, wx[0][3], a3); a3 = fdot2(xp1, wx[1][3], a3);
          a4 = fdot2(xp0, wx[0][4], a4); a4 = fdot2(xp1, wx[1][4], a4);
          a5 = fdot2(xp0, wx[0][5], a5); a5 = fdot2(xp1, wx[1][5], a5);
          a6 = fdot2(xp0, wx[0][6], a6); a6 = fdot2(xp1, wx[1][6], a6);
          a7 = fdot2(xp0, wx[0][7], a7); a7 = fdot2(xp1, wx[1][7], a7);
        }
        float s0 = row16_sum(a0), s1 = row16_sum(a1);
        float s2 = row16_sum(a2), s3 = row16_sum(a3);
        float s4 = row16_sum(a4), s5 = row16_sum(a5);
        float s6 = row16_sum(a6), s7 = row16_sum(a7);
        float h = fast_tanh(sel8(ks, s0, s1, s2, s3, s4, s5, s6, s7) + bj);
        u16 hbits = f2hb(h);
        if (writer) hcH[nx * 320 + woffH] = hbits;
        hreg[s] = hbits;
        if (s == 7) {
          if (writer) {
            u16* dst = hb + (size_t)(t - 7) * Hn + jcol;
            #pragma unroll
            for (int i = 0; i < 8; ++i) dst[i * Hn] = hreg[i];
          }
          if ((t8 & 3) == 3 && t8 < 127)
            ((uint2*)(xsH + (xcur ^ 1) * 2048))[tid] =
                make_uint2(h2bits(pk2(xr.x, xr.y)), h2bits(pk2(xr.z, xr.w)));
        }
        __syncthreads();  // vmcnt(0) drained -> safe to release
        if (s == 7 && (t8 & 3) == 3 && tid == 0)
          __hip_atomic_store(flags + b, (t8 >> 2) + 1, __ATOMIC_RELEASE,
                             __HIP_MEMORY_SCOPE_AGENT);
      }
    }
  } else {
    // ========== ROLE BC: dense u2 prologue (LDS) + clean serial scan2 =====
    const int b = bid - Bn;
    const u16* hb1 = h1b16 + (size_t)b * Tn * Hn;
    u16* hsH = smemU;            // [32][320] halfs = 20 KB (h1 staging)
    u16* u2S = smemU + 10240;    // [32][272] halfs = 17 KB (u2 buffer)
    u16* hcU = smemU + 18944;    // 2 x 320 halfs (h2 state)

    unsigned w2b[8][8];  // Wx2 k-pairs -> AGPR-resident (throughput path)
    h2 wh[8][8];         // Wh2 k-pairs -> arch-VGPR (serial-critical path)
    #pragma unroll
    for (int p = 0; p < 8; ++p) {
      const float* r0 = Wx2 + (size_t)(16 * ks + 2 * p) * Hn + col0;
      float4 a0 = *(const float4*)r0, a1 = *(const float4*)(r0 + 4);
      float4 c0 = *(const float4*)(r0 + Hn), c1 = *(const float4*)(r0 + Hn + 4);
      w2b[p][0] = h2bits(pk2(a0.x, c0.x)); w2b[p][1] = h2bits(pk2(a0.y, c0.y));
      w2b[p][2] = h2bits(pk2(a0.z, c0.z)); w2b[p][3] = h2bits(pk2(a0.w, c0.w));
      w2b[p][4] = h2bits(pk2(a1.x, c1.x)); w2b[p][5] = h2bits(pk2(a1.y, c1.y));
      w2b[p][6] = h2bits(pk2(a1.z, c1.z)); w2b[p][7] = h2bits(pk2(a1.w, c1.w));
    }
    #pragma unroll
    for (int p = 0; p < 8; ++p) {
      const float* r0 = Wh2 + (size_t)(16 * ks + 2 * p) * Hn + col0;
      float4 a0 = *(const float4*)r0, a1 = *(const float4*)(r0 + 4);
      float4 c0 = *(const float4*)(r0 + Hn), c1 = *(const float4*)(r0 + Hn + 4);
      wh[p][0] = pk2(a0.x, c0.x); wh[p][1] = pk2(a0.y, c0.y);
      wh[p][2] = pk2(a0.z, c0.z); wh[p][3] = pk2(a0.w, c0.w);
      wh[p][4] = pk2(a1.x, c1.x); wh[p][5] = pk2(a1.y, c1.y);
      wh[p][6] = pk2(a1.z, c1.z); wh[p][7] = pk2(a1.w, c1.w);
    }
    #pragma unroll
    for (int p = 0; p < 8; ++p)
      #pragma unroll
      for (int c = 0; c < 8; ++c) { pinA(w2b[p][c]); pin16(wh[p][c]); }

    const float b2j = b2[jcol];
    const int woffH = 20 * (jcol >> 4) + (jcol & 15);
    const int lr = tid >> 4;            // step row within chunk
    const int lc = tid & 15;            // 16-half column chunk
    u16* ldst = hsH + lr * 320 + 20 * lc;

    for (int i = tid; i < 640; i += 512) hcU[i] = 0;  // zero h2 state

    for (int blk = 0; blk < 32; ++blk) {
      if (tid == 0) {
        while (__hip_atomic_load(flags + b, __ATOMIC_ACQUIRE,
                                 __HIP_MEMORY_SCOPE_AGENT) < blk + 1)
          __builtin_amdgcn_s_sleep(8);
      }
      __syncthreads();
      {  // stage h1 chunk [32 steps][256] -> hsH
        const uint4* src = (const uint4*)(hb1 + (size_t)(blk * 32 + lr) * Hn + 16 * lc);
        uint4 v0 = src[0], v1 = src[1];  // 32 B = 16 halfs
        ((uint2*)ldst)[0] = make_uint2(v0.x, v0.y);
        ((uint2*)ldst)[1] = make_uint2(v0.z, v0.w);
        ((uint2*)ldst)[2] = make_uint2(v1.x, v1.y);
        ((uint2*)ldst)[3] = make_uint2(v1.z, v1.w);
      }
      __syncthreads();
      // Dense prologue: u2 for ALL 32 steps of this chunk (throughput burst;
      // w2 reads pay v_accvgpr_read here where there is slack).
      #pragma unroll 4
      for (int q = 0; q < 32; ++q) {
        float v = colval256u(hsH + q * 320, ks, w2b);
        if (writer) u2S[q * 272 + jcol] = f2hb(v + b2j);
      }
      __syncthreads();
      // 32 CLEAN serial scan steps (round-0 scan2 body; wh in arch VGPRs).
      for (int g = 0; g < 4; ++g) {
        #pragma unroll
        for (int s = 0; s < 8; ++s) {
          const int step = g * 8 + s;
          const int cu = step & 1, nx = cu ^ 1;
          float uval = hb2f(u2S[step * 272 + jcol]);
          float acc = colval256(hcU + cu * 320, ks, wh);
          float h = fast_tanh(acc + uval);
          if (writer) hcU[nx * 320 + woffH] = f2hb(h);
          __syncthreads();
        }
      }
    }
    if (tid < Hn)
      hfinal[(size_t)b * Hn + tid] = hb2f(hcU[(tid >> 4) * 20 + (tid & 15)]);
  }
}

// ---------------------------------------------------------------------------
// Head: out = softmax(h2_T @ Wd + bd). f32, unchanged.
// ---------------------------------------------------------------------------
__global__ __launch_bounds__(128) void head_kernel(
    const float* __restrict__ hfinal, const float* __restrict__ Wd,
    const float* __restrict__ bd, float* __restrict__ out) {
  __shared__ float hrow[Hn];
  __shared__ float red[On];
  const int o = threadIdx.x;
  const int b = blockIdx.x;
  hrow[o] = hfinal[(size_t)b * Hn + o];
  hrow[o + 128] = hfinal[(size_t)b * Hn + 128 + o];
  __syncthreads();
  float acc = bd[o];
  #pragma unroll 8
  for (int k = 0; k < Hn; ++k) acc = fmaf(hrow[k], Wd[(size_t)k * On + o], acc);
  red[o] = acc;
  __syncthreads();
  #pragma unroll
  for (int s = 64; s > 0; s >>= 1) {
    if (o < s) red[o] = fmaxf(red[o], red[o + s]);
    __syncthreads();
  }
  const float mx = red[0];
  __syncthreads();
  const float e = __expf(acc - mx);
  red[o] = e;
  __syncthreads();
  #pragma unroll
  for (int s = 64; s > 0; s >>= 1) {
    if (o < s) red[o] += red[o + s];
    __syncthreads();
  }
  out[(size_t)b * On + o] = e / red[0];
}

// ---------------------------------------------------------------------------
extern "C" void kernel_launch(void* const* d_in, const int* in_sizes, int n_in,
                              void* d_out, int out_size, void* d_ws, size_t ws_size,
                              hipStream_t stream) {
  const float* x   = (const float*)d_in[0];
  const float* Wx1 = (const float*)d_in[1];
  const float* Wh1 = (const float*)d_in[2];
  const float* b1  = (const float*)d_in[3];
  const float* Wx2 = (const float*)d_in[4];
  const float* Wh2 = (const float*)d_in[5];
  const float* b2  = (const float*)d_in[6];
  const float* Wd  = (const float*)d_in[7];
  const float* bd  = (const float*)d_in[8];
  float* out = (float*)d_out;

  u16* h1b16 = (u16*)d_ws;                            // [B,T,256] f16 (64 MB)
  float* hfinal = (float*)(h1b16 + (size_t)Bn * Tn * Hn);  // [B,256] f32
  int* flags = (int*)(hfinal + (size_t)Bn * Hn);      // [B] A->BC

  hipMemsetAsync(flags, 0, Bn * sizeof(int), stream);
  stage1_kernel<<<2 * Bn, 512, 0, stream>>>(x, Wx1, Wh1, b1, Wx2, b2, Wh2,
                                            h1b16, flags, hfinal);
  head_kernel<<<Bn, 128, 0, stream>>>(hfinal, Wd, bd, out);
}

// Round 7
// 1155.325 us; speedup vs baseline: 1.2418x; 1.1262x over previous
//
#include <hip/hip_runtime.h>
#include <cstdint>

constexpr int Bn = 128, Tn = 1024, Dn = 64, Hn = 256, On = 128;

typedef __fp16 h2 __attribute__((ext_vector_type(2)));
typedef unsigned short u16;

__device__ __forceinline__ float fast_tanh(float x) {
  float e = __expf(2.0f * x);
  return 1.0f - 2.0f / (e + 1.0f);
}

// v_dot2_f32_f16: 2 f16 MACs with f32 accumulate, full VALU rate.
__device__ __forceinline__ float fdot2(h2 a, h2 b, float c) {
#if __has_builtin(__builtin_amdgcn_fdot2)
  return __builtin_amdgcn_fdot2(a, b, c, false);
#else
  return fmaf((float)a.y, (float)b.y, fmaf((float)a.x, (float)b.x, c));
#endif
}

__device__ __forceinline__ h2 pk2(float a, float b) {
  h2 r; r.x = (__fp16)a; r.y = (__fp16)b; return r;
}
__device__ __forceinline__ h2 bits2h(unsigned u) { return __builtin_bit_cast(h2, u); }
__device__ __forceinline__ unsigned h2bits(h2 v) { return __builtin_bit_cast(unsigned, v); }
__device__ __forceinline__ u16 f2hb(float f) {
  __fp16 h = (__fp16)f; return __builtin_bit_cast(u16, h);
}
__device__ __forceinline__ float hb2f(u16 b) {
  return (float)__builtin_bit_cast(__fp16, b);
}
__device__ __forceinline__ void pin16(h2& w) { asm volatile("" : "+v"(w)); }

template <int CTRL>
__device__ __forceinline__ float dpp_add(float v) {
  int s = __builtin_amdgcn_update_dpp(0, __float_as_int(v), CTRL, 0xF, 0xF, true);
  return v + __int_as_float(s);
}
__device__ __forceinline__ float row16_sum(float v) {
  v = dpp_add<0xB1>(v);   // quad_perm xor1
  v = dpp_add<0x4E>(v);   // quad_perm xor2
  v = dpp_add<0x141>(v);  // ROW_HALF_MIRROR == xor4
  v = dpp_add<0x140>(v);  // ROW_MIRROR == xor8
  return v;
}
__device__ __forceinline__ float sel8(int ks, float s0, float s1, float s2,
                                      float s3, float s4, float s5, float s6,
                                      float s7) {
  float u0 = (ks & 1) ? s1 : s0;
  float u1 = (ks & 1) ? s3 : s2;
  float u2 = (ks & 1) ? s5 : s4;
  float u3 = (ks & 1) ? s7 : s6;
  float v0 = (ks & 2) ? u1 : u0;
  float v1 = (ks & 2) ? u3 : u2;
  return (ks & 4) ? v1 : v0;
}

// Full 256-k matvec for one LDS row (stride-320-half layout, 20*ks chunks):
// every lane computes 8 column partials, DPP-reduces over the 16 ks lanes,
// and returns this lane's selected column value (pre-bias).
__device__ __forceinline__ float colval256(const u16* rowbase, int ks,
                                           const h2 (&w)[8][8]) {
  const uint2* hq = (const uint2*)(rowbase + 20 * ks);
  uint2 q0 = hq[0], q1 = hq[1], q2 = hq[2], q3 = hq[3];
  float a0 = 0.f, a1 = 0.f, a2 = 0.f, a3 = 0.f,
        a4 = 0.f, a5 = 0.f, a6 = 0.f, a7 = 0.f;
  const unsigned d[8] = {q0.x, q0.y, q1.x, q1.y, q2.x, q2.y, q3.x, q3.y};
  #pragma unroll
  for (int p = 0; p < 8; ++p) {
    h2 hp = bits2h(d[p]);
    a0 = fdot2(hp, w[p][0], a0);
    a1 = fdot2(hp, w[p][1], a1);
    a2 = fdot2(hp, w[p][2], a2);
    a3 = fdot2(hp, w[p][3], a3);
    a4 = fdot2(hp, w[p][4], a4);
    a5 = fdot2(hp, w[p][5], a5);
    a6 = fdot2(hp, w[p][6], a6);
    a7 = fdot2(hp, w[p][7], a7);
  }
  float s0 = row16_sum(a0), s1 = row16_sum(a1);
  float s2 = row16_sum(a2), s3 = row16_sum(a3);
  float s4 = row16_sum(a4), s5 = row16_sum(a5);
  float s6 = row16_sum(a6), s7 = row16_sum(a7);
  return sel8(ks, s0, s1, s2, s3, s4, s5, s6, s7);
}

// LDS h layout (f16): 16 slices x (16 data + 4 pad) halfs; slice stride 40 B
// -> reader dwords 10*ks mod 32 all distinct, conflict-free; 8 B aligned.
// ---------------------------------------------------------------------------
// Fused pipeline, 256 WGs x 1024 threads == 1 block/CU guaranteed.
//   role A  (blocks 0..127): waves 8-15 EXIT IMMEDIATELY (before any
//       barrier; exited waves are not counted by s_barrier — standard ROCm
//       early-exit pattern). Waves 0-7 then run the exact round-0 scan1
//       producer with its original barrier structure. (Round 6's textually-
//       divergent idle-wave barrier skeleton was the prime hang suspect —
//       removed.)
//   role BC (blocks 128..255): WAVE-SPECIALIZED, all barriers in common code.
//       waves 0-7  (512 thr): serial scan2, exact round-0 body, Wh2 weights
//                             in THEIR arch VGPRs (64 regs).
//       waves 8-15 (512 thr): dense u2 = h1@Wx2+b2 -> LDS, round-0 role-B
//                             matvec, Wx2 weights in THEIR arch VGPRs.
//       Same register numbers, different per-wave contents -> no 128-reg
//       conflict (rounds 2/4/5: same-thread fusion always cost ~40 us/chunk
//       because program order serializes; m114: separate waves co-schedule
//       at ~max, not sum).
//       Schedule per chunk: dense spins flag, stages h1, computes u2 row 0;
//       then 32 slices: serial step s || dense u2 row s+1; one barrier each.
//       Dense slice issue (~840cy/SIMD both groups) hides inside serial's
//       ~1460cy latency-bound step.
// ---------------------------------------------------------------------------
__global__ __launch_bounds__(1024, 4) void stage1_kernel(
    const float* __restrict__ x,    // [B,T,64] f32
    const float* __restrict__ Wx1,  // [64,256] f32
    const float* __restrict__ Wh1,  // [256,256] f32
    const float* __restrict__ b1,   // [256]
    const float* __restrict__ Wx2,  // [256,256] f32
    const float* __restrict__ b2,   // [256]
    const float* __restrict__ Wh2,  // [256,256] f32
    u16* __restrict__ h1b16,        // [B,T,256] f16 h1 (A -> BC channel)
    int* __restrict__ flags,        // [B]  A -> BC progress (32-step blocks)
    float* __restrict__ hfinal) {   // [B,256] f32 (role BC output)
  __shared__ alignas(16) u16 smemU[19584];  // 38.25 KB
  const int tid = threadIdx.x;
  const unsigned bid = blockIdx.x;

  // Role-A blocks use only waves 0-7; waves 8-15 exit BEFORE any barrier.
  if (bid < (unsigned)Bn && tid >= 512) return;

  if (bid < (unsigned)Bn) {
    // ================= ROLE A: scan1 producer (waves 0-7) =================
    const int ks = tid & 15;
    const int cg = tid >> 4;
    const int col0 = 8 * cg;
    const int jcol = col0 + (ks & 7);
    const bool writer = (ks < 8);
    const int b = bid;
    const float* xb = x + (size_t)b * Tn * Dn;
    u16* hb = h1b16 + (size_t)b * Tn * Hn;
    u16* hcH = smemU;          // 2 x 320 halfs
    u16* xsH = smemU + 768;    // 2 x 2048 halfs (32-step x blocks, f16)

    h2 wh[8][8];  // Wh1 k-pairs (16ks+2p, +1) x 8 cols
    #pragma unroll
    for (int p = 0; p < 8; ++p) {
      const float* r0 = Wh1 + (size_t)(16 * ks + 2 * p) * Hn + col0;
      float4 a0 = *(const float4*)r0, a1 = *(const float4*)(r0 + 4);
      float4 c0 = *(const float4*)(r0 + Hn), c1 = *(const float4*)(r0 + Hn + 4);
      wh[p][0] = pk2(a0.x, c0.x); wh[p][1] = pk2(a0.y, c0.y);
      wh[p][2] = pk2(a0.z, c0.z); wh[p][3] = pk2(a0.w, c0.w);
      wh[p][4] = pk2(a1.x, c1.x); wh[p][5] = pk2(a1.y, c1.y);
      wh[p][6] = pk2(a1.z, c1.z); wh[p][7] = pk2(a1.w, c1.w);
    }
    h2 wx[2][8];  // Wx1 k-pairs (4ks+2p, +1)
    #pragma unroll
    for (int p = 0; p < 2; ++p) {
      const float* r0 = Wx1 + (size_t)(4 * ks + 2 * p) * Hn + col0;
      float4 a0 = *(const float4*)r0, a1 = *(const float4*)(r0 + 4);
      float4 c0 = *(const float4*)(r0 + Hn), c1 = *(const float4*)(r0 + Hn + 4);
      wx[p][0] = pk2(a0.x, c0.x); wx[p][1] = pk2(a0.y, c0.y);
      wx[p][2] = pk2(a0.z, c0.z); wx[p][3] = pk2(a0.w, c0.w);
      wx[p][4] = pk2(a1.x, c1.x); wx[p][5] = pk2(a1.y, c1.y);
      wx[p][6] = pk2(a1.z, c1.z); wx[p][7] = pk2(a1.w, c1.w);
    }
    #pragma unroll
    for (int p = 0; p < 8; ++p)
      #pragma unroll
      for (int c = 0; c < 8; ++c) pin16(wh[p][c]);
    #pragma unroll
    for (int p = 0; p < 2; ++p)
      #pragma unroll
      for (int c = 0; c < 8; ++c) pin16(wx[p][c]);

    const float bj = b1[jcol];
    const int woffH = 20 * (jcol >> 4) + (jcol & 15);

    for (int i = tid; i < 640; i += 512) hcH[i] = 0;  // zero both h buffers
    {
      float4 x0 = *(const float4*)(xb + 4 * tid);  // block 0 -> f16 LDS
      ((uint2*)xsH)[tid] = make_uint2(h2bits(pk2(x0.x, x0.y)), h2bits(pk2(x0.z, x0.w)));
    }
    __syncthreads();

    u16 hreg[8];
    float4 xr = make_float4(0.f, 0.f, 0.f, 0.f);
    for (int t8 = 0; t8 < 128; ++t8) {
      const int xcur = (t8 >> 2) & 1;
      #pragma unroll
      for (int s = 0; s < 8; ++s) {
        const int t = t8 * 8 + s;
        const int cu = s & 1, nx = cu ^ 1;
        if (s == 0 && (t8 & 3) == 0 && t8 < 124)
          xr = *(const float4*)(xb + (size_t)((t8 >> 2) + 1) * 2048 + 4 * tid);

        const uint2* hq = (const uint2*)(hcH + cu * 320 + 20 * ks);
        uint2 q0 = hq[0], q1 = hq[1], q2 = hq[2], q3 = hq[3];
        uint2 xq = *(const uint2*)(xsH + xcur * 2048 + ((t & 31) << 6) + 4 * ks);
        float a0 = 0.f, a1 = 0.f, a2 = 0.f, a3 = 0.f,
              a4 = 0.f, a5 = 0.f, a6 = 0.f, a7 = 0.f;
        const unsigned d[8] = {q0.x, q0.y, q1.x, q1.y, q2.x, q2.y, q3.x, q3.y};
        #pragma unroll
        for (int p = 0; p < 8; ++p) {
          h2 hp = bits2h(d[p]);
          a0 = fdot2(hp, wh[p][0], a0);
          a1 = fdot2(hp, wh[p][1], a1);
          a2 = fdot2(hp, wh[p][2], a2);
          a3 = fdot2(hp, wh[p][3], a3);
          a4 = fdot2(hp, wh[p][4], a4);
          a5 = fdot2(hp, wh[p][5], a5);
          a6 = fdot2(hp, wh[p][6], a6);
          a7 = fdot2(hp, wh[p][7], a7);
        }
        {
          h2 xp0 = bits2h(xq.x), xp1 = bits2h(xq.y);
          a0 = fdot2(xp0, wx[0][0], a0); a0 = fdot2(xp1, wx[1][0], a0);
          a1 = fdot2(xp0, wx[0][1], a1); a1 = fdot2(xp1, wx[1][1], a1);
          a2 = fdot2(xp0, wx[0][2], a2); a2 = fdot2(xp1, wx[1][2], a2);
          a3 = fdot2(xp0, wx[0][3], a3); a3 = fdot2(xp1, wx[1][3], a3);
          a4 = fdot2(xp0, wx[0][4], a4); a4 = fdot2(xp1, wx[1][4], a4);
          a5 = fdot2(xp0, wx[0][5], a5); a5 = fdot2(xp1, wx[1][5], a5);
          a6 = fdot2(xp0, wx[0][6], a6); a6 = fdot2(xp1, wx[1][6], a6);
          a7 = fdot2(xp0, wx[0][7], a7); a7 = fdot2(xp1, wx[1][7], a7);
        }
        float s0 = row16_sum(a0), s1 = row16_sum(a1);
        float s2 = row16_sum(a2), s3 = row16_sum(a3);
        float s4 = row16_sum(a4), s5 = row16_sum(a5);
        float s6 = row16_sum(a6), s7 = row16_sum(a7);
        float h = fast_tanh(sel8(ks, s0, s1, s2, s3, s4, s5, s6, s7) + bj);
        u16 hbits = f2hb(h);
        if (writer) hcH[nx * 320 + woffH] = hbits;
        hreg[s] = hbits;
        if (s == 7) {
          if (writer) {
            u16* dst = hb + (size_t)(t - 7) * Hn + jcol;
            #pragma unroll
            for (int i = 0; i < 8; ++i) dst[i * Hn] = hreg[i];
          }
          if ((t8 & 3) == 3 && t8 < 127)
            ((uint2*)(xsH + (xcur ^ 1) * 2048))[tid] =
                make_uint2(h2bits(pk2(xr.x, xr.y)), h2bits(pk2(xr.z, xr.w)));
        }
        __syncthreads();  // vmcnt(0) drained -> safe to release
        if (s == 7 && (t8 & 3) == 3 && tid == 0)
          __hip_atomic_store(flags + bid, (t8 >> 2) + 1, __ATOMIC_RELEASE,
                             __HIP_MEMORY_SCOPE_AGENT);
      }
    }
  } else {
    // ========== ROLE BC: wave-specialized serial scan2 || dense u2 ========
    const int b = bid - Bn;
    const u16* hb1 = h1b16 + (size_t)b * Tn * Hn;
    u16* hsH = smemU;            // [32][320] halfs = 20 KB (h1 staging)
    u16* u2S = smemU + 10240;    // [32][272] halfs = 17 KB (u2 buffer)
    u16* hcU = smemU + 18944;    // 2 x 320 halfs (h2 state)

    const bool serialG = (tid < 512);
    const int lt = tid & 511;
    const int ks = lt & 15;
    const int cg = lt >> 4;
    const int col0 = 8 * cg;
    const int jcol = col0 + (ks & 7);
    const bool writer = (ks < 8);
    const int woffH = 20 * (jcol >> 4) + (jcol & 15);

    // Wave-divergent weight source: serial waves hold Wh2, dense waves Wx2.
    const float* Wsrc = serialG ? Wh2 : Wx2;
    h2 w[8][8];
    #pragma unroll
    for (int p = 0; p < 8; ++p) {
      const float* r0 = Wsrc + (size_t)(16 * ks + 2 * p) * Hn + col0;
      float4 a0 = *(const float4*)r0, a1 = *(const float4*)(r0 + 4);
      float4 c0 = *(const float4*)(r0 + Hn), c1 = *(const float4*)(r0 + Hn + 4);
      w[p][0] = pk2(a0.x, c0.x); w[p][1] = pk2(a0.y, c0.y);
      w[p][2] = pk2(a0.z, c0.z); w[p][3] = pk2(a0.w, c0.w);
      w[p][4] = pk2(a1.x, c1.x); w[p][5] = pk2(a1.y, c1.y);
      w[p][6] = pk2(a1.z, c1.z); w[p][7] = pk2(a1.w, c1.w);
    }
    #pragma unroll
    for (int p = 0; p < 8; ++p)
      #pragma unroll
      for (int c = 0; c < 8; ++c) pin16(w[p][c]);

    const float b2j = b2[jcol];  // used by dense waves only

    // Staging coords (dense waves)
    const int lr = lt >> 4;   // step row within chunk (0..31)
    const int lc = lt & 15;   // 16-half column chunk
    u16* ldst = hsH + lr * 320 + 20 * lc;

    if (serialG)
      for (int i = lt; i < 640; i += 512) hcU[i] = 0;  // zero h2 state
    __syncthreads();

    for (int blk = 0; blk < 32; ++blk) {
      // --- pre-phase: dense waves acquire h1 chunk & seed u2 row 0 ---
      if (!serialG && lt == 0) {
        while (__hip_atomic_load(flags + b, __ATOMIC_ACQUIRE,
                                 __HIP_MEMORY_SCOPE_AGENT) < blk + 1)
          __builtin_amdgcn_s_sleep(8);
      }
      __syncthreads();  // B1: flag acquired for all
      if (!serialG) {   // stage h1 chunk [32 steps][256] -> hsH
        const uint4* src =
            (const uint4*)(hb1 + (size_t)(blk * 32 + lr) * Hn + 16 * lc);
        uint4 v0 = src[0], v1 = src[1];  // 32 B = 16 halfs
        ((uint2*)ldst)[0] = make_uint2(v0.x, v0.y);
        ((uint2*)ldst)[1] = make_uint2(v0.z, v0.w);
        ((uint2*)ldst)[2] = make_uint2(v1.x, v1.y);
        ((uint2*)ldst)[3] = make_uint2(v1.z, v1.w);
      }
      __syncthreads();  // B2: staging visible
      if (!serialG) {   // u2 row 0
        float v = colval256(hsH, ks, w);
        if (writer) u2S[jcol] = f2hb(v + b2j);
      }
      __syncthreads();  // B3: row 0 visible

      // --- 32 slices: serial step s || dense u2 row s+1 ---
      for (int g = 0; g < 4; ++g) {
        #pragma unroll
        for (int s8 = 0; s8 < 8; ++s8) {
          const int s = g * 8 + s8;
          if (serialG) {
            const int cu = s & 1, nx = cu ^ 1;
            float uval = hb2f(u2S[s * 272 + jcol]);
            float acc = colval256(hcU + cu * 320, ks, w);
            float h = fast_tanh(acc + uval);
            if (writer) hcU[nx * 320 + woffH] = f2hb(h);
          } else if (s < 31) {
            float v = colval256(hsH + (s + 1) * 320, ks, w);
            if (writer) u2S[(s + 1) * 272 + jcol] = f2hb(v + b2j);
          }
          __syncthreads();
        }
      }
    }
    if (tid < Hn)
      hfinal[(size_t)b * Hn + tid] = hb2f(hcU[(tid >> 4) * 20 + (tid & 15)]);
  }
}

// ---------------------------------------------------------------------------
// Head: out = softmax(h2_T @ Wd + bd). f32, unchanged.
// ---------------------------------------------------------------------------
__global__ __launch_bounds__(128) void head_kernel(
    const float* __restrict__ hfinal, const float* __restrict__ Wd,
    const float* __restrict__ bd, float* __restrict__ out) {
  __shared__ float hrow[Hn];
  __shared__ float red[On];
  const int o = threadIdx.x;
  const int b = blockIdx.x;
  hrow[o] = hfinal[(size_t)b * Hn + o];
  hrow[o + 128] = hfinal[(size_t)b * Hn + 128 + o];
  __syncthreads();
  float acc = bd[o];
  #pragma unroll 8
  for (int k = 0; k < Hn; ++k) acc = fmaf(hrow[k], Wd[(size_t)k * On + o], acc);
  red[o] = acc;
  __syncthreads();
  #pragma unroll
  for (int s = 64; s > 0; s >>= 1) {
    if (o < s) red[o] = fmaxf(red[o], red[o + s]);
    __syncthreads();
  }
  const float mx = red[0];
  __syncthreads();
  const float e = __expf(acc - mx);
  red[o] = e;
  __syncthreads();
  #pragma unroll
  for (int s = 64; s > 0; s >>= 1) {
    if (o < s) red[o] += red[o + s];
    __syncthreads();
  }
  out[(size_t)b * On + o] = e / red[0];
}

// ---------------------------------------------------------------------------
extern "C" void kernel_launch(void* const* d_in, const int* in_sizes, int n_in,
                              void* d_out, int out_size, void* d_ws, size_t ws_size,
                              hipStream_t stream) {
  const float* x   = (const float*)d_in[0];
  const float* Wx1 = (const float*)d_in[1];
  const float* Wh1 = (const float*)d_in[2];
  const float* b1  = (const float*)d_in[3];
  const float* Wx2 = (const float*)d_in[4];
  const float* Wh2 = (const float*)d_in[5];
  const float* b2  = (const float*)d_in[6];
  const float* Wd  = (const float*)d_in[7];
  const float* bd  = (const float*)d_in[8];
  float* out = (float*)d_out;

  u16* h1b16 = (u16*)d_ws;                            // [B,T,256] f16 (64 MB)
  float* hfinal = (float*)(h1b16 + (size_t)Bn * Tn * Hn);  // [B,256] f32
  int* flags = (int*)(hfinal + (size_t)Bn * Hn);      // [B] A->BC

  hipMemsetAsync(flags, 0, Bn * sizeof(int), stream);
  stage1_kernel<<<2 * Bn, 1024, 0, stream>>>(x, Wx1, Wh1, b1, Wx2, b2, Wh2,
                                             h1b16, flags, hfinal);
  head_kernel<<<Bn, 128, 0, stream>>>(hfinal, Wd, bd, out);
}